// Round 1
// baseline (160.589 us; speedup 1.0000x reference)
//
#include <hip/hip_runtime.h>
#include <hip/hip_bf16.h>

#define S_TOT 50000
#define S_PAD 50048      // 782 * 64
#define NTILES 782
#define HD 128

typedef float f32x4 __attribute__((ext_vector_type(4)));
typedef short s16x8 __attribute__((ext_vector_type(8)));

__device__ __forceinline__ f32x4 mfma_bf16(s16x8 a, s16x8 b, f32x4 c) {
  return __builtin_amdgcn_mfma_f32_16x16x32_bf16(a, b, c, 0, 0, 0);
}

// rows of (emb[sel] @ W^T + bias) * scalef -> bf16 dst ; pad rows -> 0
__global__ __launch_bounds__(128) void prep_rows(
    const float* __restrict__ emb, const float* __restrict__ W,
    const float* __restrict__ bias, const int* __restrict__ idcs,
    __hip_bfloat16* __restrict__ dst, int total_rows, int valid_rows,
    float scalef)
{
  __shared__ __align__(16) float els[16][HD];
  const int h = threadIdx.x;
  const int r0 = blockIdx.x * 16;
  for (int rr = 0; rr < 16; ++rr) {
    int row = r0 + rr;
    float v = 0.f;
    if (row < valid_rows) {
      int er = idcs ? idcs[row] : row;
      v = emb[(size_t)er * HD + h];
    }
    els[rr][h] = v;
  }
  __syncthreads();
  float acc[16];
#pragma unroll
  for (int rr = 0; rr < 16; ++rr) acc[rr] = 0.f;
  const f32x4* W4 = (const f32x4*)(W + (size_t)h * HD);
  for (int e4 = 0; e4 < HD / 4; ++e4) {
    f32x4 wv = W4[e4];
#pragma unroll
    for (int rr = 0; rr < 16; ++rr) {
      f32x4 ev = *(const f32x4*)&els[rr][e4 * 4];
      acc[rr] += ev[0] * wv[0] + ev[1] * wv[1] + ev[2] * wv[2] + ev[3] * wv[3];
    }
  }
  float bh = bias[h];
  for (int rr = 0; rr < 16; ++rr) {
    int row = r0 + rr;
    if (row < total_rows) {
      float ov = (row < valid_rows) ? (acc[rr] + bh) * scalef : 0.f;
      dst[(size_t)row * HD + h] = __float2bfloat16(ov);
    }
  }
}

// pass1: l[row] = sum_s exp(q[row] . keys[s])   (scale pre-folded into q)
__global__ __launch_bounds__(256) void pass1(
    const __hip_bfloat16* __restrict__ keys,
    const __hip_bfloat16* __restrict__ qrs,
    float* __restrict__ lsum)
{
  __shared__ __align__(16) unsigned char kt[64 * 256];
  const int tid = threadIdx.x;
  const int wid = tid >> 6;
  const int lane = tid & 63;
  const int r16 = lane & 15;
  const int g = lane >> 4;
  const int rowbase = blockIdx.x * 128 + wid * 32;

  s16x8 af[2][4];
#pragma unroll
  for (int rt = 0; rt < 2; ++rt) {
    const unsigned short* qp =
        (const unsigned short*)qrs + (size_t)(rowbase + rt * 16 + r16) * HD;
#pragma unroll
    for (int c = 0; c < 4; ++c)
      af[rt][c] = *(const s16x8*)(qp + c * 32 + g * 8);
  }
  float sums[2][4] = {};
  for (int t = blockIdx.y; t < NTILES; t += (int)gridDim.y) {
    const int s0 = t * 64;
    __syncthreads();
    {
      const unsigned char* src = (const unsigned char*)(keys + (size_t)s0 * HD);
#pragma unroll
      for (int u = 0; u < 4; ++u) {
        int linear = u * 4096 + tid * 16;
        int row = linear >> 8;
        int b16 = linear & 255;
        int swz = b16 ^ ((row & 7) << 4);
        *(f32x4*)(kt + row * 256 + swz) = *(const f32x4*)(src + linear);
      }
    }
    __syncthreads();
#pragma unroll
    for (int j = 0; j < 4; ++j) {
      f32x4 a0 = {0.f, 0.f, 0.f, 0.f};
      f32x4 a1 = {0.f, 0.f, 0.f, 0.f};
      const int srow = j * 16 + r16;
      const unsigned char* kr = kt + srow * 256;
      const int sw = (srow & 7) << 4;
#pragma unroll
      for (int c = 0; c < 4; ++c) {
        s16x8 bf = *(const s16x8*)(kr + ((c * 64 + g * 16) ^ sw));
        a0 = mfma_bf16(af[0][c], bf, a0);
        a1 = mfma_bf16(af[1][c], bf, a1);
      }
      if (s0 + j * 16 + r16 < S_TOT) {
#pragma unroll
        for (int r = 0; r < 4; ++r) {
          sums[0][r] += __expf(a0[r]);
          sums[1][r] += __expf(a1[r]);
        }
      }
    }
  }
#pragma unroll
  for (int rt = 0; rt < 2; ++rt) {
#pragma unroll
    for (int r = 0; r < 4; ++r) {
      float v = sums[rt][r];
      v += __shfl_xor(v, 1, 64);
      v += __shfl_xor(v, 2, 64);
      v += __shfl_xor(v, 4, 64);
      v += __shfl_xor(v, 8, 64);
      if (r16 == 0) atomicAdd(&lsum[rowbase + rt * 16 + g * 4 + r], v);
    }
  }
}

// pass2: out[b,s] = sum_k (belief[b,k]/l[b,k]) * exp(score)
__global__ __launch_bounds__(256) void pass2(
    const __hip_bfloat16* __restrict__ keys,
    const __hip_bfloat16* __restrict__ qrs,
    const float* __restrict__ lsum,
    const float* __restrict__ belief,
    float* __restrict__ out)
{
  __shared__ __align__(16) unsigned char kt[64 * 256];
  __shared__ float outs[64];
  const int tid = threadIdx.x;
  const int wid = tid >> 6;
  const int lane = tid & 63;
  const int r16 = lane & 15;
  const int g = lane >> 4;
  const int b = blockIdx.x;
  const int kbase = wid * 32;

  s16x8 af[2][4];
  float wq[2][4];
#pragma unroll
  for (int rt = 0; rt < 2; ++rt) {
    const unsigned short* qp =
        (const unsigned short*)qrs + (size_t)(b * 128 + kbase + rt * 16 + r16) * HD;
#pragma unroll
    for (int c = 0; c < 4; ++c)
      af[rt][c] = *(const s16x8*)(qp + c * 32 + g * 8);
#pragma unroll
    for (int r = 0; r < 4; ++r) {
      int row = b * 128 + kbase + rt * 16 + 4 * g + r;
      wq[rt][r] = belief[row] / lsum[row];
    }
  }
  for (int t = blockIdx.y; t < NTILES; t += (int)gridDim.y) {
    const int s0 = t * 64;
    __syncthreads();
    {
      const unsigned char* src = (const unsigned char*)(keys + (size_t)s0 * HD);
#pragma unroll
      for (int u = 0; u < 4; ++u) {
        int linear = u * 4096 + tid * 16;
        int row = linear >> 8;
        int b16 = linear & 255;
        int swz = b16 ^ ((row & 7) << 4);
        *(f32x4*)(kt + row * 256 + swz) = *(const f32x4*)(src + linear);
      }
    }
    if (tid < 64) outs[tid] = 0.f;
    __syncthreads();
#pragma unroll
    for (int j = 0; j < 4; ++j) {
      f32x4 a0 = {0.f, 0.f, 0.f, 0.f};
      f32x4 a1 = {0.f, 0.f, 0.f, 0.f};
      const int srow = j * 16 + r16;
      const unsigned char* kr = kt + srow * 256;
      const int sw = (srow & 7) << 4;
#pragma unroll
      for (int c = 0; c < 4; ++c) {
        s16x8 bf = *(const s16x8*)(kr + ((c * 64 + g * 16) ^ sw));
        a0 = mfma_bf16(af[0][c], bf, a0);
        a1 = mfma_bf16(af[1][c], bf, a1);
      }
      float v = 0.f;
#pragma unroll
      for (int r = 0; r < 4; ++r) {
        v += wq[0][r] * __expf(a0[r]);
        v += wq[1][r] * __expf(a1[r]);
      }
      v += __shfl_xor(v, 16, 64);
      v += __shfl_xor(v, 32, 64);
      if (g == 0) atomicAdd(&outs[j * 16 + r16], v);
    }
    __syncthreads();
    if (tid < 64) {
      int s = s0 + tid;
      if (s < S_TOT) out[(size_t)b * S_TOT + s] = outs[tid];
    }
  }
}

extern "C" void kernel_launch(void* const* d_in, const int* in_sizes, int n_in,
                              void* d_out, int out_size, void* d_ws, size_t ws_size,
                              hipStream_t stream) {
  const float* state_emb = (const float*)d_in[0];
  const float* Wk = (const float*)d_in[1];
  const float* bk = (const float*)d_in[2];
  const float* Wq = (const float*)d_in[3];
  const float* bq = (const float*)d_in[4];
  const float* belief = (const float*)d_in[5];
  const int* idcs = (const int*)d_in[6];
  float* out = (float*)d_out;

  __hip_bfloat16* keys = (__hip_bfloat16*)d_ws;                 // S_PAD*128 bf16
  __hip_bfloat16* qrs = keys + (size_t)S_PAD * HD;              // 2048*128 bf16
  float* lsum = (float*)(qrs + (size_t)2048 * HD);              // 2048 f32

  hipMemsetAsync(lsum, 0, 2048 * sizeof(float), stream);
  prep_rows<<<S_PAD / 16, 128, 0, stream>>>(state_emb, Wk, bk, nullptr, keys,
                                            S_PAD, S_TOT, 1.0f);
  prep_rows<<<2048 / 16, 128, 0, stream>>>(state_emb, Wq, bq, idcs, qrs,
                                           2048, 2048, 0.08838834764831843f);
  pass1<<<dim3(16, 128), 256, 0, stream>>>(keys, qrs, lsum);
  pass2<<<dim3(16, 128), 256, 0, stream>>>(keys, qrs, lsum, belief, out);
}

// Round 2
// 112.449 us; speedup vs baseline: 1.4281x; 1.4281x over previous
//
#include <hip/hip_runtime.h>
#include <hip/hip_bf16.h>

#define S_TOT 50000
#define S_PAD 50048      // 782 * 64
#define NTILES 782
#define HD 128

typedef float f32x4 __attribute__((ext_vector_type(4)));
typedef short s16x8 __attribute__((ext_vector_type(8)));

__device__ __forceinline__ f32x4 mfma_bf16(s16x8 a, s16x8 b, f32x4 c) {
  return __builtin_amdgcn_mfma_f32_16x16x32_bf16(a, b, c, 0, 0, 0);
}

__device__ __forceinline__ short f2bf(float x) {
  __hip_bfloat16 h = __float2bfloat16(x);
  return *reinterpret_cast<short*>(&h);
}

__device__ __forceinline__ s16x8 pack8v(f32x4 a, f32x4 b) {
  s16x8 v;
  v[0] = f2bf(a[0]); v[1] = f2bf(a[1]); v[2] = f2bf(a[2]); v[3] = f2bf(a[3]);
  v[4] = f2bf(b[0]); v[5] = f2bf(b[1]); v[6] = f2bf(b[2]); v[7] = f2bf(b[3]);
  return v;
}

// dst[row,:] = (emb[sel(row)] @ W^T + bias) * scalef  as bf16; rows >= valid -> 0.
// W (128x128 f32, L2-resident) held entirely in registers as 32 b-frags.
__global__ __launch_bounds__(256) void prep_mfma(
    const float* __restrict__ emb, const float* __restrict__ W,
    const float* __restrict__ bias, const int* __restrict__ idcs,
    __hip_bfloat16* __restrict__ dst, int ntiles, int valid_rows, float scalef)
{
  const int tid = threadIdx.x;
  const int wid = tid >> 6;
  const int lane = tid & 63;
  const int r16 = lane & 15;
  const int g = lane >> 4;

  s16x8 bfr[8][4];
#pragma unroll
  for (int jg = 0; jg < 8; ++jg) {
    const float* wp = W + (size_t)(jg * 16 + r16) * HD;
#pragma unroll
    for (int c = 0; c < 4; ++c) {
      f32x4 w0 = *(const f32x4*)(wp + c * 32 + g * 8);
      f32x4 w1 = *(const f32x4*)(wp + c * 32 + g * 8 + 4);
      bfr[jg][c] = pack8v(w0, w1);
    }
  }
  float bsc[8];
#pragma unroll
  for (int jg = 0; jg < 8; ++jg) bsc[jg] = bias[jg * 16 + r16] * scalef;

  for (int tt = blockIdx.x * 4 + wid; tt < ntiles; tt += (int)gridDim.x * 4) {
    int row = tt * 16 + r16;
    int er = (row < valid_rows) ? (idcs ? idcs[row] : row) : (valid_rows - 1);
    const float* ep = emb + (size_t)er * HD;
    s16x8 af[4];
#pragma unroll
    for (int c = 0; c < 4; ++c) {
      f32x4 e0 = *(const f32x4*)(ep + c * 32 + g * 8);
      f32x4 e1 = *(const f32x4*)(ep + c * 32 + g * 8 + 4);
      af[c] = pack8v(e0, e1);
    }
#pragma unroll
    for (int jg = 0; jg < 8; ++jg) {
      f32x4 acc = {0.f, 0.f, 0.f, 0.f};
#pragma unroll
      for (int c = 0; c < 4; ++c) acc = mfma_bf16(af[c], bfr[jg][c], acc);
#pragma unroll
      for (int r = 0; r < 4; ++r) {
        int ro = tt * 16 + 4 * g + r;
        float val = (ro < valid_rows) ? acc[r] * scalef + bsc[jg] : 0.f;
        dst[(size_t)ro * HD + jg * 16 + r16] = __float2bfloat16(val);
      }
    }
  }
}

// pass1: l[row] = sum_s exp(q[row] . keys[s])   (scale pre-folded into q)
// 64 q-rows per wave (4 row-tiles), 4:1 MFMA:ds_read.
__global__ __launch_bounds__(256) void pass1(
    const __hip_bfloat16* __restrict__ keys,
    const __hip_bfloat16* __restrict__ qrs,
    float* __restrict__ lsum)
{
  __shared__ __align__(16) unsigned char kt[64 * 256];
  const int tid = threadIdx.x;
  const int wid = tid >> 6;
  const int lane = tid & 63;
  const int r16 = lane & 15;
  const int g = lane >> 4;
  const int rowbase = blockIdx.x * 256 + wid * 64;

  s16x8 af[4][4];
#pragma unroll
  for (int rt = 0; rt < 4; ++rt) {
    const unsigned short* qp =
        (const unsigned short*)qrs + (size_t)(rowbase + rt * 16 + r16) * HD;
#pragma unroll
    for (int c = 0; c < 4; ++c)
      af[rt][c] = *(const s16x8*)(qp + c * 32 + g * 8);
  }
  float sums[4][4] = {};
  for (int t = blockIdx.y; t < NTILES; t += (int)gridDim.y) {
    const int s0 = t * 64;
    __syncthreads();
    {
      const unsigned char* src = (const unsigned char*)(keys + (size_t)s0 * HD);
#pragma unroll
      for (int u = 0; u < 4; ++u) {
        int linear = u * 4096 + tid * 16;
        int row = linear >> 8;
        int b16 = linear & 255;
        int swz = b16 ^ ((row & 7) << 4);
        *(f32x4*)(kt + row * 256 + swz) = *(const f32x4*)(src + linear);
      }
    }
    __syncthreads();
#pragma unroll
    for (int j = 0; j < 4; ++j) {
      f32x4 a[4];
#pragma unroll
      for (int rt = 0; rt < 4; ++rt) a[rt] = f32x4{0.f, 0.f, 0.f, 0.f};
      const int srow = j * 16 + r16;
      const unsigned char* kr = kt + srow * 256;
      const int sw = (srow & 7) << 4;
#pragma unroll
      for (int c = 0; c < 4; ++c) {
        s16x8 bf = *(const s16x8*)(kr + ((c * 64 + g * 16) ^ sw));
#pragma unroll
        for (int rt = 0; rt < 4; ++rt) a[rt] = mfma_bf16(af[rt][c], bf, a[rt]);
      }
      if (s0 + j * 16 + r16 < S_TOT) {
#pragma unroll
        for (int rt = 0; rt < 4; ++rt)
#pragma unroll
          for (int r = 0; r < 4; ++r) sums[rt][r] += __expf(a[rt][r]);
      }
    }
  }
#pragma unroll
  for (int rt = 0; rt < 4; ++rt) {
#pragma unroll
    for (int r = 0; r < 4; ++r) {
      float v = sums[rt][r];
      v += __shfl_xor(v, 1, 64);
      v += __shfl_xor(v, 2, 64);
      v += __shfl_xor(v, 4, 64);
      v += __shfl_xor(v, 8, 64);
      if (r16 == 0) atomicAdd(&lsum[rowbase + rt * 16 + g * 4 + r], v);
    }
  }
}

// pass2: out[b,s] = sum_k (belief[b,k]/l[b,k]) * exp(score)
// 2 batches per block; each wave stays within one batch (64 k-rows).
__global__ __launch_bounds__(256) void pass2(
    const __hip_bfloat16* __restrict__ keys,
    const __hip_bfloat16* __restrict__ qrs,
    const float* __restrict__ lsum,
    const float* __restrict__ belief,
    float* __restrict__ out)
{
  __shared__ __align__(16) unsigned char kt[64 * 256];
  __shared__ float outs[2][64];
  const int tid = threadIdx.x;
  const int wid = tid >> 6;
  const int lane = tid & 63;
  const int r16 = lane & 15;
  const int g = lane >> 4;
  const int rowbase = blockIdx.x * 256 + wid * 64;
  const int bloc = wid >> 1;

  s16x8 af[4][4];
  float wq[4][4];
#pragma unroll
  for (int rt = 0; rt < 4; ++rt) {
    const unsigned short* qp =
        (const unsigned short*)qrs + (size_t)(rowbase + rt * 16 + r16) * HD;
#pragma unroll
    for (int c = 0; c < 4; ++c)
      af[rt][c] = *(const s16x8*)(qp + c * 32 + g * 8);
#pragma unroll
    for (int r = 0; r < 4; ++r) {
      int row = rowbase + rt * 16 + 4 * g + r;
      wq[rt][r] = belief[row] / lsum[row];
    }
  }
  for (int t = blockIdx.y; t < NTILES; t += (int)gridDim.y) {
    const int s0 = t * 64;
    __syncthreads();
    {
      const unsigned char* src = (const unsigned char*)(keys + (size_t)s0 * HD);
#pragma unroll
      for (int u = 0; u < 4; ++u) {
        int linear = u * 4096 + tid * 16;
        int row = linear >> 8;
        int b16 = linear & 255;
        int swz = b16 ^ ((row & 7) << 4);
        *(f32x4*)(kt + row * 256 + swz) = *(const f32x4*)(src + linear);
      }
    }
    if (tid < 128) outs[tid >> 6][tid & 63] = 0.f;
    __syncthreads();
#pragma unroll
    for (int j = 0; j < 4; ++j) {
      f32x4 a[4];
#pragma unroll
      for (int rt = 0; rt < 4; ++rt) a[rt] = f32x4{0.f, 0.f, 0.f, 0.f};
      const int srow = j * 16 + r16;
      const unsigned char* kr = kt + srow * 256;
      const int sw = (srow & 7) << 4;
#pragma unroll
      for (int c = 0; c < 4; ++c) {
        s16x8 bf = *(const s16x8*)(kr + ((c * 64 + g * 16) ^ sw));
#pragma unroll
        for (int rt = 0; rt < 4; ++rt) a[rt] = mfma_bf16(af[rt][c], bf, a[rt]);
      }
      float v = 0.f;
#pragma unroll
      for (int rt = 0; rt < 4; ++rt)
#pragma unroll
        for (int r = 0; r < 4; ++r) v += wq[rt][r] * __expf(a[rt][r]);
      v += __shfl_xor(v, 16, 64);
      v += __shfl_xor(v, 32, 64);
      if (g == 0) atomicAdd(&outs[bloc][j * 16 + r16], v);
    }
    __syncthreads();
    if (tid < 128) {
      int s = s0 + (tid & 63);
      if (s < S_TOT)
        out[(size_t)(blockIdx.x * 2 + (tid >> 6)) * S_TOT + s] =
            outs[tid >> 6][tid & 63];
    }
  }
}

extern "C" void kernel_launch(void* const* d_in, const int* in_sizes, int n_in,
                              void* d_out, int out_size, void* d_ws, size_t ws_size,
                              hipStream_t stream) {
  const float* state_emb = (const float*)d_in[0];
  const float* Wk = (const float*)d_in[1];
  const float* bk = (const float*)d_in[2];
  const float* Wq = (const float*)d_in[3];
  const float* bq = (const float*)d_in[4];
  const float* belief = (const float*)d_in[5];
  const int* idcs = (const int*)d_in[6];
  float* out = (float*)d_out;

  __hip_bfloat16* keys = (__hip_bfloat16*)d_ws;                 // S_PAD*128 bf16
  __hip_bfloat16* qrs = keys + (size_t)S_PAD * HD;              // 2048*128 bf16
  float* lsum = (float*)(qrs + (size_t)2048 * HD);              // 2048 f32

  hipMemsetAsync(lsum, 0, 2048 * sizeof(float), stream);
  prep_mfma<<<256, 256, 0, stream>>>(state_emb, Wk, bk, nullptr, keys,
                                     S_PAD / 16, S_TOT, 1.0f);
  prep_mfma<<<32, 256, 0, stream>>>(state_emb, Wq, bq, idcs, qrs,
                                    128, 2048, 0.08838834764831843f);
  pass1<<<dim3(8, 96), 256, 0, stream>>>(keys, qrs, lsum);
  pass2<<<dim3(8, 96), 256, 0, stream>>>(keys, qrs, lsum, belief, out);
}